// Round 1
// baseline (595.832 us; speedup 1.0000x reference)
//
#include <hip/hip_runtime.h>
#include <math.h>

namespace {
constexpr int EDIM  = 512;
constexpr int DDIM  = 1024;
constexpr int ADIM  = 128;
constexpr int FDIM  = 32;
constexpr int KW    = 31;
constexpr int BATCH = 128;
constexpr int TDIM  = 512;

constexpr int BM = 64;   // t-tile
constexpr int BK = 32;   // k-tile

__device__ __forceinline__ float fast_tanh(float x) {
  x = fminf(9.0f, fmaxf(-9.0f, x));
  float e = __expf(2.0f * x);
  return (e - 1.0f) / (e + 1.0f);
}

// dec_p[b,a] = sum_d dec[b,d] * Wdec[a,d]
__global__ __launch_bounds__(256)
void dec_proj_kernel(const float* __restrict__ dec,
                     const float* __restrict__ Wdec,
                     float* __restrict__ dec_p) {
  int b = blockIdx.x;
  int tid = threadIdx.x;      // 256
  int a = tid >> 1;           // 0..127
  int h = tid & 1;            // half of D
  const float* dv = dec + (size_t)b * DDIM + h * (DDIM / 2);
  const float* wv = Wdec + (size_t)a * DDIM + h * (DDIM / 2);
  float s = 0.f;
  #pragma unroll 4
  for (int i = 0; i < DDIM / 2; i += 4) {
    float4 d4 = *(const float4*)(dv + i);
    float4 w4 = *(const float4*)(wv + i);
    s += d4.x * w4.x + d4.y * w4.y + d4.z * w4.z + d4.w * w4.w;
  }
  s += __shfl_xor(s, 1, 64);
  if (h == 0) dec_p[b * ADIM + a] = s;
}

// energies[b,t] = sum_a tanh(enc_p + dec_p + loc_p) * We[a] + be
__global__ __launch_bounds__(256)
void energies_kernel(const float* __restrict__ enc,     // [B,T,E]
                     const float* __restrict__ Wenc,    // [A,E]
                     const float* __restrict__ pa,      // [B,T]
                     const float* __restrict__ convw,   // [F,1,K]
                     const float* __restrict__ Wloc,    // [A,F]
                     const float* __restrict__ We,      // [A]
                     const float* __restrict__ be,      // [1]
                     const float* __restrict__ dec_p,   // [B,A]
                     float* __restrict__ energies) {    // [B,T]
  __shared__ union {
    struct { float encs[BM][36];  float Ws[ADIM][36]; } mm;    // main GEMM tiles
    struct { float locs[BM][36];  float wlocs[ADIM][36]; } ep; // epilogue tiles
  } u;
  __shared__ float pa_s[96];
  __shared__ float cw_s[FDIM][33];
  __shared__ float We_s[ADIM];
  __shared__ float dp_s[ADIM];

  const int tid = threadIdx.x;
  const int b   = blockIdx.y;
  const int t0  = blockIdx.x * BM;
  const int tx  = tid & 15;   // a-group: a = j*16 + tx
  const int ty  = tid >> 4;   // t-group: t = ty*4 + i

  // stage small arrays (visible by first __syncthreads below)
  if (tid < 96) {
    int gt = t0 - 15 + tid;
    pa_s[tid] = (gt >= 0 && gt < TDIM) ? pa[b * TDIM + gt] : 0.0f;
  }
  for (int id = tid; id < FDIM * KW; id += 256)
    cw_s[id / KW][id % KW] = convw[id];
  if (tid < ADIM) {
    We_s[tid] = We[tid];
    dp_s[tid] = dec_p[b * ADIM + tid];
  }

  float acc[4][8];
  #pragma unroll
  for (int i = 0; i < 4; ++i)
    #pragma unroll
    for (int j = 0; j < 8; ++j) acc[i][j] = 0.f;

  const float* encB = enc + ((size_t)b * TDIM + t0) * EDIM;

  for (int k0 = 0; k0 < EDIM; k0 += BK) {
    // stage enc tile: 64 x 32 floats = 512 float4
    #pragma unroll
    for (int r = 0; r < 2; ++r) {
      int id = tid + 256 * r;
      int row = id >> 3, c4 = id & 7;
      float4 v = *(const float4*)(encB + (size_t)row * EDIM + k0 + c4 * 4);
      *(float4*)&u.mm.encs[row][c4 * 4] = v;
    }
    // stage Wenc tile: 128 x 32 floats = 1024 float4
    #pragma unroll
    for (int r = 0; r < 4; ++r) {
      int id = tid + 256 * r;
      int row = id >> 3, c4 = id & 7;
      float4 v = *(const float4*)(Wenc + (size_t)row * EDIM + k0 + c4 * 4);
      *(float4*)&u.mm.Ws[row][c4 * 4] = v;
    }
    __syncthreads();
    #pragma unroll
    for (int kc = 0; kc < BK / 4; ++kc) {
      float4 ev[4];
      float4 wv[8];
      #pragma unroll
      for (int i = 0; i < 4; ++i)
        ev[i] = *(const float4*)&u.mm.encs[ty * 4 + i][kc * 4];
      #pragma unroll
      for (int j = 0; j < 8; ++j)
        wv[j] = *(const float4*)&u.mm.Ws[j * 16 + tx][kc * 4];
      #pragma unroll
      for (int i = 0; i < 4; ++i)
        #pragma unroll
        for (int j = 0; j < 8; ++j)
          acc[i][j] += ev[i].x * wv[j].x + ev[i].y * wv[j].y +
                       ev[i].z * wv[j].z + ev[i].w * wv[j].w;
    }
    __syncthreads();
  }

  // epilogue staging: Wloc -> wlocs, conv(pa) -> locs (union re-use; safe after sync)
  #pragma unroll
  for (int r = 0; r < 4; ++r) {
    int id = tid + 256 * r;
    int row = id >> 3, c4 = id & 7;
    float4 v = *(const float4*)(Wloc + row * FDIM + c4 * 4);
    *(float4*)&u.ep.wlocs[row][c4 * 4] = v;
  }
  {
    int tl = tid >> 2;          // 0..63
    int fg = tid & 3;
    #pragma unroll
    for (int n = 0; n < 8; ++n) {
      int f = fg * 8 + n;
      float s = 0.f;
      #pragma unroll
      for (int k = 0; k < KW; ++k) s += pa_s[tl + k] * cw_s[f][k];
      u.ep.locs[tl][f] = s;
    }
  }
  __syncthreads();

  const float be0 = be[0];
  float esum[4] = {0.f, 0.f, 0.f, 0.f};
  #pragma unroll
  for (int i = 0; i < 4; ++i) {
    int tl = ty * 4 + i;
    #pragma unroll
    for (int j = 0; j < 8; ++j) {
      int a = j * 16 + tx;
      float lp = 0.f;
      #pragma unroll
      for (int f4 = 0; f4 < FDIM / 4; ++f4) {
        float4 l4 = *(const float4*)&u.ep.locs[tl][f4 * 4];
        float4 w4 = *(const float4*)&u.ep.wlocs[a][f4 * 4];
        lp += l4.x * w4.x + l4.y * w4.y + l4.z * w4.z + l4.w * w4.w;
      }
      float x = acc[i][j] + dp_s[a] + lp;
      esum[i] += fast_tanh(x) * We_s[a];
    }
  }
  // reduce over the 16 a-group lanes (tx) within each wave
  #pragma unroll
  for (int m = 1; m < 16; m <<= 1) {
    #pragma unroll
    for (int i = 0; i < 4; ++i) esum[i] += __shfl_xor(esum[i], m, 64);
  }
  if (tx == 0) {
    #pragma unroll
    for (int i = 0; i < 4; ++i)
      energies[(size_t)b * TDIM + t0 + ty * 4 + i] = esum[i] + be0;
  }
}

// in-place softmax over T for each b
__global__ __launch_bounds__(256)
void softmax_kernel(float* __restrict__ attn) {
  int b = blockIdx.x;
  int tid = threadIdx.x;
  float* row = attn + (size_t)b * TDIM;
  float x0 = row[tid], x1 = row[tid + 256];
  float m = fmaxf(x0, x1);
  #pragma unroll
  for (int off = 32; off; off >>= 1) m = fmaxf(m, __shfl_xor(m, off, 64));
  __shared__ float redm[4];
  __shared__ float reds[4];
  int wid = tid >> 6, lane = tid & 63;
  if (lane == 0) redm[wid] = m;
  __syncthreads();
  m = fmaxf(fmaxf(redm[0], redm[1]), fmaxf(redm[2], redm[3]));
  float e0 = __expf(x0 - m), e1 = __expf(x1 - m);
  float s = e0 + e1;
  #pragma unroll
  for (int off = 32; off; off >>= 1) s += __shfl_xor(s, off, 64);
  if (lane == 0) reds[wid] = s;
  __syncthreads();
  s = reds[0] + reds[1] + reds[2] + reds[3];
  float inv = 1.0f / s;
  row[tid] = e0 * inv;
  row[tid + 256] = e1 * inv;
}

// ctx[b,e] += sum_t attn[b,t] * enc[b,t,e]  (T split in 4 chunks, atomicAdd)
__global__ __launch_bounds__(256)
void context_kernel(const float* __restrict__ enc,
                    const float* __restrict__ attn,
                    float* __restrict__ ctx) {
  int e = blockIdx.x * 256 + threadIdx.x;
  int b = blockIdx.y;
  int tc = blockIdx.z * 128;
  const float* w = attn + (size_t)b * TDIM + tc;
  const float* ep = enc + ((size_t)b * TDIM + tc) * EDIM + e;
  float acc = 0.f;
  #pragma unroll 8
  for (int t = 0; t < 128; ++t) acc += w[t] * ep[(size_t)t * EDIM];
  atomicAdd(&ctx[(size_t)b * EDIM + e], acc);
}

}  // namespace

extern "C" void kernel_launch(void* const* d_in, const int* in_sizes, int n_in,
                              void* d_out, int out_size, void* d_ws, size_t ws_size,
                              hipStream_t stream) {
  const float* enc   = (const float*)d_in[0];  // [B,T,E]
  const float* dec   = (const float*)d_in[1];  // [B,D]
  const float* pa    = (const float*)d_in[2];  // [B,T]
  const float* Wenc  = (const float*)d_in[3];  // [A,E]
  const float* Wdec  = (const float*)d_in[4];  // [A,D]
  const float* convw = (const float*)d_in[5];  // [F,1,K]
  const float* Wloc  = (const float*)d_in[6];  // [A,F]
  const float* We    = (const float*)d_in[7];  // [1,A]
  const float* be    = (const float*)d_in[8];  // [1]

  float* ctx   = (float*)d_out;                         // [B,E]
  float* attn  = (float*)d_out + BATCH * EDIM;          // [B,T] (energies -> softmax in place)
  float* dec_p = (float*)d_ws;                          // [B,A] scratch (64 KB)

  hipMemsetAsync(ctx, 0, (size_t)BATCH * EDIM * sizeof(float), stream);

  dec_proj_kernel<<<BATCH, 256, 0, stream>>>(dec, Wdec, dec_p);

  dim3 g3(TDIM / BM, BATCH);
  energies_kernel<<<g3, 256, 0, stream>>>(enc, Wenc, pa, convw, Wloc, We, be,
                                          dec_p, attn);

  softmax_kernel<<<BATCH, 256, 0, stream>>>(attn);

  dim3 g5(EDIM / 256, BATCH, TDIM / 128);
  context_kernel<<<g5, 256, 0, stream>>>(enc, attn, ctx);
}

// Round 2
// 372.016 us; speedup vs baseline: 1.6016x; 1.6016x over previous
//
#include <hip/hip_runtime.h>
#include <hip/hip_bf16.h>
#include <math.h>

namespace {
constexpr int EDIM  = 512;
constexpr int DDIM  = 1024;
constexpr int ADIM  = 128;
constexpr int FDIM  = 32;
constexpr int KW    = 31;
constexpr int BATCH = 128;
constexpr int TDIM  = 512;

constexpr int BM  = 64;   // t-tile
constexpr int BK  = 32;   // k-tile
constexpr int LDA = 40;   // LDS row stride in ushorts (80 B: 16B-aligned, 2-way banks = free)

typedef __attribute__((ext_vector_type(8))) short short8;
typedef __attribute__((ext_vector_type(4))) float floatx4;

__device__ __forceinline__ float fast_tanh(float x) {
  x = fminf(9.0f, fmaxf(-9.0f, x));
  float e = __expf(2.0f * x);
  return (e - 1.0f) / (e + 1.0f);
}

__device__ __forceinline__ ushort2 pack_bf16(float x, float y) {
  union { __hip_bfloat162 h; ushort2 u; } cv;
  cv.h = __float22bfloat162_rn(make_float2(x, y));
  return cv.u;
}

// convert float4 -> 4 bf16 and store 8 B to LDS
__device__ __forceinline__ void stage4(ushort* dst, const float4 v) {
  ushort2 lo = pack_bf16(v.x, v.y);
  ushort2 hi = pack_bf16(v.z, v.w);
  *(ushort4*)dst = make_ushort4(lo.x, lo.y, hi.x, hi.y);
}

// dec_p[b,a] = sum_d dec[b,d] * Wdec[a,d]   grid (B, 4), 256 thr
__global__ __launch_bounds__(256)
void dec_proj_kernel(const float* __restrict__ dec,
                     const float* __restrict__ Wdec,
                     float* __restrict__ dec_p) {
  int b = blockIdx.x, az = blockIdx.y;
  int tid = threadIdx.x;
  int al = tid >> 3, seg = tid & 7;       // 32 a's/block, 8 lanes per a
  int a = az * 32 + al;
  const float* dv = dec + (size_t)b * DDIM;
  const float* wv = Wdec + (size_t)a * DDIM;
  float s = 0.f;
  #pragma unroll 8
  for (int it = 0; it < 32; ++it) {
    int d = it * 32 + seg * 4;            // 8 consecutive lanes cover 128 B
    float4 d4 = *(const float4*)(dv + d);
    float4 w4 = *(const float4*)(wv + d);
    s += d4.x * w4.x + d4.y * w4.y + d4.z * w4.z + d4.w * w4.w;
  }
  s += __shfl_xor(s, 1, 64);
  s += __shfl_xor(s, 2, 64);
  s += __shfl_xor(s, 4, 64);
  if (seg == 0) dec_p[b * ADIM + a] = s;
}

// energies[b,t] = sum_a tanh(enc_p + dec_p + loc_p) * We[a] + be
// enc_p and loc_p both accumulated via bf16 MFMA (loc_p = 17th K-iteration).
__global__ __launch_bounds__(256)
void energies_kernel(const float* __restrict__ enc,     // [B,T,E]
                     const float* __restrict__ Wenc,    // [A,E]
                     const float* __restrict__ pa,      // [B,T]
                     const float* __restrict__ convw,   // [F,1,K]
                     const float* __restrict__ Wloc,    // [A,F]
                     const float* __restrict__ We,      // [A]
                     const float* __restrict__ be,      // [1]
                     const float* __restrict__ dec_p,   // [B,A]
                     float* __restrict__ energies) {    // [B,T]
  __shared__ ushort As[BM][LDA];          // 5120 B
  __shared__ ushort Bs[ADIM][LDA];        // 10240 B
  __shared__ float pa_s[96];
  __shared__ float cw_s[FDIM][KW + 2];    // stride 33
  __shared__ float We_s[ADIM];
  __shared__ float dp_s[ADIM];
  __shared__ float epart[2][BM];

  const int tid  = threadIdx.x;
  const int b    = blockIdx.y;
  const int t0   = blockIdx.x * BM;
  const int wave = tid >> 6;
  const int lane = tid & 63;
  const int wt   = wave >> 1;   // t-half  (32 rows)
  const int wa   = wave & 1;    // a-half  (64 cols)
  const int lc   = lane & 15;
  const int lq   = lane >> 4;

  if (tid < 96) {
    int gt = t0 - 15 + tid;
    pa_s[tid] = (gt >= 0 && gt < TDIM) ? pa[b * TDIM + gt] : 0.0f;
  }
  for (int id = tid; id < FDIM * KW; id += 256)
    cw_s[id / KW][id % KW] = convw[id];
  if (tid < ADIM) {
    We_s[tid] = We[tid];
    dp_s[tid] = dec_p[b * ADIM + tid];
  }

  floatx4 acc[2][4];
  #pragma unroll
  for (int tt = 0; tt < 2; ++tt)
    #pragma unroll
    for (int aT = 0; aT < 4; ++aT)
      acc[tt][aT] = (floatx4){0.f, 0.f, 0.f, 0.f};

  const float* encB = enc + ((size_t)b * TDIM + t0) * EDIM;
  ushort2 cvp[4];   // conv result, bf16-packed (filled at kt==0)

  for (int kt = 0; kt < 17; ++kt) {
    if (kt < 16) {
      const int k0 = kt * BK;
      #pragma unroll
      for (int r = 0; r < 2; ++r) {     // enc tile 64x32
        int id = tid + 256 * r;
        int row = id >> 3, c4 = id & 7;
        float4 v = *(const float4*)(encB + (size_t)row * EDIM + k0 + c4 * 4);
        stage4(&As[row][c4 * 4], v);
      }
      #pragma unroll
      for (int r = 0; r < 4; ++r) {     // Wenc tile 128x32
        int id = tid + 256 * r;
        int row = id >> 3, c4 = id & 7;
        float4 v = *(const float4*)(Wenc + (size_t)row * EDIM + k0 + c4 * 4);
        stage4(&Bs[row][c4 * 4], v);
      }
    } else {
      // 17th iteration: A = conv(prev_attn) [64 x F], B = Wloc [128 x F]
      int tl = tid >> 2, fg = tid & 3;
      *(ushort2*)&As[tl][fg * 8 + 0] = cvp[0];
      *(ushort2*)&As[tl][fg * 8 + 2] = cvp[1];
      *(ushort2*)&As[tl][fg * 8 + 4] = cvp[2];
      *(ushort2*)&As[tl][fg * 8 + 6] = cvp[3];
      #pragma unroll
      for (int r = 0; r < 4; ++r) {
        int id = tid + 256 * r;
        int row = id >> 3, c4 = id & 7;
        float4 v = *(const float4*)(Wloc + (size_t)row * FDIM + c4 * 4);
        stage4(&Bs[row][c4 * 4], v);
      }
    }
    __syncthreads();

    if (kt == 0) {
      // compute location conv into registers (pa_s/cw_s now valid; used at kt==16)
      int tl = tid >> 2, fg = tid & 3;
      float cv[8];
      #pragma unroll
      for (int n = 0; n < 8; ++n) {
        int f = fg * 8 + n;
        float s = 0.f;
        #pragma unroll
        for (int k = 0; k < KW; ++k) s += pa_s[tl + k] * cw_s[f][k];
        cv[n] = s;
      }
      cvp[0] = pack_bf16(cv[0], cv[1]);
      cvp[1] = pack_bf16(cv[2], cv[3]);
      cvp[2] = pack_bf16(cv[4], cv[5]);
      cvp[3] = pack_bf16(cv[6], cv[7]);
    }

    short8 af[2], bf[4];
    #pragma unroll
    for (int tt = 0; tt < 2; ++tt)
      af[tt] = *(const short8*)&As[wt * 32 + tt * 16 + lc][lq * 8];
    #pragma unroll
    for (int aT = 0; aT < 4; ++aT)
      bf[aT] = *(const short8*)&Bs[wa * 64 + aT * 16 + lc][lq * 8];
    #pragma unroll
    for (int tt = 0; tt < 2; ++tt)
      #pragma unroll
      for (int aT = 0; aT < 4; ++aT)
        acc[tt][aT] = __builtin_amdgcn_mfma_f32_16x16x32_bf16(
            af[tt], bf[aT], acc[tt][aT], 0, 0, 0);
    __syncthreads();
  }

  // epilogue: e[t] = sum_a tanh(acc + dec_p[a]) * We[a]
  float dpv[4], wev[4];
  #pragma unroll
  for (int aT = 0; aT < 4; ++aT) {
    int a = wa * 64 + aT * 16 + lc;
    dpv[aT] = dp_s[a];
    wev[aT] = We_s[a];
  }
  #pragma unroll
  for (int tt = 0; tt < 2; ++tt) {
    float es[4] = {0.f, 0.f, 0.f, 0.f};
    #pragma unroll
    for (int aT = 0; aT < 4; ++aT)
      #pragma unroll
      for (int i = 0; i < 4; ++i)
        es[i] += fast_tanh(acc[tt][aT][i] + dpv[aT]) * wev[aT];
    #pragma unroll
    for (int m = 1; m < 16; m <<= 1)
      #pragma unroll
      for (int i = 0; i < 4; ++i) es[i] += __shfl_xor(es[i], m, 64);
    if (lc == 0)
      #pragma unroll
      for (int i = 0; i < 4; ++i)
        epart[wa][wt * 32 + tt * 16 + lq * 4 + i] = es[i];
  }
  __syncthreads();
  if (tid < BM)
    energies[(size_t)b * TDIM + t0 + tid] = epart[0][tid] + epart[1][tid] + be[0];
}

// in-place softmax over T for each b
__global__ __launch_bounds__(256)
void softmax_kernel(float* __restrict__ attn) {
  int b = blockIdx.x;
  int tid = threadIdx.x;
  float* row = attn + (size_t)b * TDIM;
  float x0 = row[tid], x1 = row[tid + 256];
  float m = fmaxf(x0, x1);
  #pragma unroll
  for (int off = 32; off; off >>= 1) m = fmaxf(m, __shfl_xor(m, off, 64));
  __shared__ float redm[4];
  __shared__ float reds[4];
  int wid = tid >> 6, lane = tid & 63;
  if (lane == 0) redm[wid] = m;
  __syncthreads();
  m = fmaxf(fmaxf(redm[0], redm[1]), fmaxf(redm[2], redm[3]));
  float e0 = __expf(x0 - m), e1 = __expf(x1 - m);
  float s = e0 + e1;
  #pragma unroll
  for (int off = 32; off; off >>= 1) s += __shfl_xor(s, off, 64);
  if (lane == 0) reds[wid] = s;
  __syncthreads();
  s = reds[0] + reds[1] + reds[2] + reds[3];
  float inv = 1.0f / s;
  row[tid] = e0 * inv;
  row[tid + 256] = e1 * inv;
}

// ctx[b,e] += sum_t attn[b,t] * enc[b,t,e]  (T split in 4 chunks, atomicAdd)
__global__ __launch_bounds__(256)
void context_kernel(const float* __restrict__ enc,
                    const float* __restrict__ attn,
                    float* __restrict__ ctx) {
  int e = blockIdx.x * 256 + threadIdx.x;
  int b = blockIdx.y;
  int tc = blockIdx.z * 128;
  const float* w = attn + (size_t)b * TDIM + tc;
  const float* ep = enc + ((size_t)b * TDIM + tc) * EDIM + e;
  float acc = 0.f;
  #pragma unroll 8
  for (int t = 0; t < 128; ++t) acc += w[t] * ep[(size_t)t * EDIM];
  atomicAdd(&ctx[(size_t)b * EDIM + e], acc);
}

}  // namespace

extern "C" void kernel_launch(void* const* d_in, const int* in_sizes, int n_in,
                              void* d_out, int out_size, void* d_ws, size_t ws_size,
                              hipStream_t stream) {
  const float* enc   = (const float*)d_in[0];
  const float* dec   = (const float*)d_in[1];
  const float* pa    = (const float*)d_in[2];
  const float* Wenc  = (const float*)d_in[3];
  const float* Wdec  = (const float*)d_in[4];
  const float* convw = (const float*)d_in[5];
  const float* Wloc  = (const float*)d_in[6];
  const float* We    = (const float*)d_in[7];
  const float* be    = (const float*)d_in[8];

  float* ctx   = (float*)d_out;                 // [B,E]
  float* attn  = (float*)d_out + BATCH * EDIM;  // [B,T]
  float* dec_p = (float*)d_ws;                  // [B,A]

  hipMemsetAsync(ctx, 0, (size_t)BATCH * EDIM * sizeof(float), stream);

  dim3 g1(BATCH, 4);
  dec_proj_kernel<<<g1, 256, 0, stream>>>(dec, Wdec, dec_p);

  dim3 g3(TDIM / BM, BATCH);
  energies_kernel<<<g3, 256, 0, stream>>>(enc, Wenc, pa, convw, Wloc, We, be,
                                          dec_p, attn);

  softmax_kernel<<<BATCH, 256, 0, stream>>>(attn);

  dim3 g5(EDIM / 256, BATCH, TDIM / 128);
  context_kernel<<<g5, 256, 0, stream>>>(enc, attn, ctx);
}

// Round 3
// 285.414 us; speedup vs baseline: 2.0876x; 1.3034x over previous
//
#include <hip/hip_runtime.h>
#include <hip/hip_bf16.h>
#include <math.h>

namespace {
constexpr int EDIM  = 512;
constexpr int DDIM  = 1024;
constexpr int ADIM  = 128;
constexpr int FDIM  = 32;
constexpr int KW    = 31;
constexpr int BATCH = 128;
constexpr int TDIM  = 512;

constexpr int BM  = 64;   // t-tile
constexpr int LDA = 40;   // fallback path LDS stride

constexpr size_t N_ENC  = (size_t)BATCH * TDIM * EDIM;   // 33554432
constexpr size_t N_WENC = (size_t)ADIM * EDIM;           // 65536
constexpr size_t N_WLOC = (size_t)ADIM * FDIM;           // 4096
constexpr size_t N_BF   = N_ENC + N_WENC + N_WLOC;       // ushorts in ws
constexpr size_t WS_NEEDED = N_BF * 2 + (size_t)BATCH * ADIM * 4;

typedef __attribute__((ext_vector_type(8))) short short8;
typedef __attribute__((ext_vector_type(4))) float floatx4;

__device__ __forceinline__ float fast_tanh(float x) {
  x = fminf(9.0f, fmaxf(-9.0f, x));
  float e = __expf(2.0f * x);
  return (e - 1.0f) / (e + 1.0f);
}

__device__ __forceinline__ ushort2 pack_bf16(float x, float y) {
  union { __hip_bfloat162 h; ushort2 u; } cv;
  cv.h = __float22bfloat162_rn(make_float2(x, y));
  return cv.u;
}

__device__ __forceinline__ void stage4(ushort* dst, const float4 v) {
  ushort2 lo = pack_bf16(v.x, v.y);
  ushort2 hi = pack_bf16(v.z, v.w);
  *(ushort4*)dst = make_ushort4(lo.x, lo.y, hi.x, hi.y);
}

// async 16-B global -> LDS (DMA; LDS dest is wave-uniform base + lane*16)
__device__ __forceinline__ void async_ld16(const void* g, void* l) {
  __builtin_amdgcn_global_load_lds(
      (const __attribute__((address_space(1))) unsigned int*)g,
      (__attribute__((address_space(3))) unsigned int*)l, 16, 0, 0);
}

// -------- pre-pass: fp32 -> bf16 for enc | Wenc | Wloc (concatenated) ------
__global__ __launch_bounds__(256)
void cvt_kernel(const float* __restrict__ enc, const float* __restrict__ Wenc,
                const float* __restrict__ Wloc, ushort* __restrict__ out) {
  size_t e0 = (size_t)blockIdx.x * 2048 + (size_t)threadIdx.x * 8;
  const float* s;
  size_t off;
  if (e0 < N_ENC) { s = enc; off = e0; }
  else if (e0 < N_ENC + N_WENC) { s = Wenc; off = e0 - N_ENC; }
  else { s = Wloc; off = e0 - (N_ENC + N_WENC); }
  float4 v0 = *(const float4*)(s + off);
  float4 v1 = *(const float4*)(s + off + 4);
  union { ushort2 u[4]; short8 v; } o;
  o.u[0] = pack_bf16(v0.x, v0.y); o.u[1] = pack_bf16(v0.z, v0.w);
  o.u[2] = pack_bf16(v1.x, v1.y); o.u[3] = pack_bf16(v1.z, v1.w);
  *(short8*)(out + e0) = o.v;
}

// dec_p[b,a] = sum_d dec[b,d] * Wdec[a,d]   grid (B, 4), 256 thr
__global__ __launch_bounds__(256)
void dec_proj_kernel(const float* __restrict__ dec,
                     const float* __restrict__ Wdec,
                     float* __restrict__ dec_p) {
  int b = blockIdx.x, az = blockIdx.y;
  int tid = threadIdx.x;
  int al = tid >> 3, seg = tid & 7;
  int a = az * 32 + al;
  const float* dv = dec + (size_t)b * DDIM;
  const float* wv = Wdec + (size_t)a * DDIM;
  float s = 0.f;
  #pragma unroll 8
  for (int it = 0; it < 32; ++it) {
    int d = it * 32 + seg * 4;
    float4 d4 = *(const float4*)(dv + d);
    float4 w4 = *(const float4*)(wv + d);
    s += d4.x * w4.x + d4.y * w4.y + d4.z * w4.z + d4.w * w4.w;
  }
  s += __shfl_xor(s, 1, 64);
  s += __shfl_xor(s, 2, 64);
  s += __shfl_xor(s, 4, 64);
  if (seg == 0) dec_p[b * ADIM + a] = s;
}

// ---------------- energies v3: async-staged bf16 MFMA ----------------------
// LDS tiles unpadded (global_load_lds needs lane-contiguous dest); bank
// conflicts broken by XOR-swizzling the GLOBAL fetch chunk: cc = gc^(row&7).
__global__ __launch_bounds__(256)
void energies_mfma_kernel(const ushort* __restrict__ enc16,   // [B,T,E] bf16
                          const ushort* __restrict__ wenc16,  // [A,E] bf16
                          const ushort* __restrict__ wloc16,  // [A,F] bf16
                          const float* __restrict__ pa,
                          const float* __restrict__ convw,
                          const float* __restrict__ We,
                          const float* __restrict__ be,
                          const float* __restrict__ dec_p,
                          float* __restrict__ energies) {
  __shared__ ushort As[BM * 64];        // 8 KB,  row stride 64 ushorts (128 B)
  __shared__ ushort Bs[ADIM * 64];      // 16 KB
  __shared__ float pa_s[96];
  __shared__ float cw_s[FDIM][KW + 2];
  __shared__ float We_s[ADIM];
  __shared__ float dp_s[ADIM];
  __shared__ float epart[2][BM];

  const int tid  = threadIdx.x;
  const int b    = blockIdx.y;
  const int t0   = blockIdx.x * BM;
  const int wave = tid >> 6, lane = tid & 63;
  const int wt = wave >> 1, wa = wave & 1;
  const int lc = lane & 15, lq = lane >> 4;
  const int sw = lc & 7;

  if (tid < 96) {
    int gt = t0 - 15 + tid;
    pa_s[tid] = (gt >= 0 && gt < TDIM) ? pa[b * TDIM + gt] : 0.0f;
  }
  for (int id = tid; id < FDIM * KW; id += 256)
    cw_s[id / KW][id % KW] = convw[id];
  if (tid < ADIM) {
    We_s[tid] = We[tid];
    dp_s[tid] = dec_p[b * ADIM + tid];
  }

  // staging descriptors (A: 2 rounds, B: 4 rounds; 16 B per thread per round)
  const int iA0 = tid, iA1 = tid + 256;
  const ushort* gA0 = enc16 + (size_t)(b * TDIM + t0 + (iA0 >> 3)) * EDIM
                      + ((iA0 & 7) ^ ((iA0 >> 3) & 7)) * 8;
  const ushort* gA1 = enc16 + (size_t)(b * TDIM + t0 + (iA1 >> 3)) * EDIM
                      + ((iA1 & 7) ^ ((iA1 >> 3) & 7)) * 8;
  ushort* lA0 = As + iA0 * 8;
  ushort* lA1 = As + iA1 * 8;
  const ushort* gB[4];
  ushort* lB[4];
  #pragma unroll
  for (int r = 0; r < 4; ++r) {
    int idx = tid + r * 256;
    int row = idx >> 3, gc = (idx & 7) ^ (row & 7);
    gB[r] = wenc16 + (size_t)row * EDIM + gc * 8;
    lB[r] = Bs + idx * 8;
  }

  floatx4 acc[2][4];
  #pragma unroll
  for (int tt = 0; tt < 2; ++tt)
    #pragma unroll
    for (int aT = 0; aT < 4; ++aT)
      acc[tt][aT] = (floatx4){0.f, 0.f, 0.f, 0.f};

  ushort2 cvp[4];

  for (int kt = 0; kt < 8; ++kt) {
    async_ld16(gA0, lA0); async_ld16(gA1, lA1);
    async_ld16(gB[0], lB[0]); async_ld16(gB[1], lB[1]);
    async_ld16(gB[2], lB[2]); async_ld16(gB[3], lB[3]);
    gA0 += 64; gA1 += 64;
    gB[0] += 64; gB[1] += 64; gB[2] += 64; gB[3] += 64;
    __syncthreads();   // drains vmcnt -> DMA data visible

    if (kt == 0) {
      int tl = tid >> 2, fg = tid & 3;
      float cv[8];
      #pragma unroll
      for (int n = 0; n < 8; ++n) {
        int f = fg * 8 + n;
        float s = 0.f;
        #pragma unroll
        for (int k = 0; k < KW; ++k) s += pa_s[tl + k] * cw_s[f][k];
        cv[n] = s;
      }
      cvp[0] = pack_bf16(cv[0], cv[1]);
      cvp[1] = pack_bf16(cv[2], cv[3]);
      cvp[2] = pack_bf16(cv[4], cv[5]);
      cvp[3] = pack_bf16(cv[6], cv[7]);
    }

    #pragma unroll
    for (int kk = 0; kk < 2; ++kk) {
      const int cco = ((kk * 4 + lq) ^ sw) * 8;
      short8 af[2], bf[4];
      #pragma unroll
      for (int tt = 0; tt < 2; ++tt)
        af[tt] = *(const short8*)&As[(wt * 32 + tt * 16 + lc) * 64 + cco];
      #pragma unroll
      for (int aT = 0; aT < 4; ++aT)
        bf[aT] = *(const short8*)&Bs[(wa * 64 + aT * 16 + lc) * 64 + cco];
      #pragma unroll
      for (int tt = 0; tt < 2; ++tt)
        #pragma unroll
        for (int aT = 0; aT < 4; ++aT)
          acc[tt][aT] = __builtin_amdgcn_mfma_f32_16x16x32_bf16(
              af[tt], bf[aT], acc[tt][aT], 0, 0, 0);
    }
    __syncthreads();
  }

  // loc iteration: A = conv(prev_attn) [64 x 32], B = Wloc [128 x 32], K=32
  {
    int tl = tid >> 2, fg = tid & 3;
    union { ushort2 u[4]; short8 v; } o;
    o.u[0] = cvp[0]; o.u[1] = cvp[1]; o.u[2] = cvp[2]; o.u[3] = cvp[3];
    *(short8*)&As[tl * 64 + (fg ^ (tl & 7)) * 8] = o.v;
    #pragma unroll
    for (int r = 0; r < 2; ++r) {
      int idx = tid + r * 256;
      int row = idx >> 2, gc = idx & 3;
      *(short8*)&Bs[row * 64 + (gc ^ (row & 7)) * 8] =
          *(const short8*)(wloc16 + row * 32 + gc * 8);
    }
    __syncthreads();
    const int cco = (lq ^ sw) * 8;
    short8 af[2], bf[4];
    #pragma unroll
    for (int tt = 0; tt < 2; ++tt)
      af[tt] = *(const short8*)&As[(wt * 32 + tt * 16 + lc) * 64 + cco];
    #pragma unroll
    for (int aT = 0; aT < 4; ++aT)
      bf[aT] = *(const short8*)&Bs[(wa * 64 + aT * 16 + lc) * 64 + cco];
    #pragma unroll
    for (int tt = 0; tt < 2; ++tt)
      #pragma unroll
      for (int aT = 0; aT < 4; ++aT)
        acc[tt][aT] = __builtin_amdgcn_mfma_f32_16x16x32_bf16(
            af[tt], bf[aT], acc[tt][aT], 0, 0, 0);
  }

  // epilogue: e[t] = sum_a tanh(acc + dec_p[a]) * We[a]
  float dpv[4], wev[4];
  #pragma unroll
  for (int aT = 0; aT < 4; ++aT) {
    int a = wa * 64 + aT * 16 + lc;
    dpv[aT] = dp_s[a];
    wev[aT] = We_s[a];
  }
  #pragma unroll
  for (int tt = 0; tt < 2; ++tt) {
    float es[4] = {0.f, 0.f, 0.f, 0.f};
    #pragma unroll
    for (int aT = 0; aT < 4; ++aT)
      #pragma unroll
      for (int i = 0; i < 4; ++i)
        es[i] += fast_tanh(acc[tt][aT][i] + dpv[aT]) * wev[aT];
    #pragma unroll
    for (int m = 1; m < 16; m <<= 1)
      #pragma unroll
      for (int i = 0; i < 4; ++i) es[i] += __shfl_xor(es[i], m, 64);
    if (lc == 0)
      #pragma unroll
      for (int i = 0; i < 4; ++i)
        epart[wa][wt * 32 + tt * 16 + lq * 4 + i] = es[i];
  }
  __syncthreads();
  if (tid < BM)
    energies[(size_t)b * TDIM + t0 + tid] = epart[0][tid] + epart[1][tid] + be[0];
}

// ---------------- fallback (R2) energies kernel, used if ws too small ------
__global__ __launch_bounds__(256)
void energies_fallback_kernel(const float* __restrict__ enc,
                              const float* __restrict__ Wenc,
                              const float* __restrict__ pa,
                              const float* __restrict__ convw,
                              const float* __restrict__ Wloc,
                              const float* __restrict__ We,
                              const float* __restrict__ be,
                              const float* __restrict__ dec_p,
                              float* __restrict__ energies) {
  __shared__ ushort As[BM][LDA];
  __shared__ ushort Bs[ADIM][LDA];
  __shared__ float pa_s[96];
  __shared__ float cw_s[FDIM][KW + 2];
  __shared__ float We_s[ADIM];
  __shared__ float dp_s[ADIM];
  __shared__ float epart[2][BM];

  const int tid  = threadIdx.x;
  const int b    = blockIdx.y;
  const int t0   = blockIdx.x * BM;
  const int wave = tid >> 6, lane = tid & 63;
  const int wt = wave >> 1, wa = wave & 1;
  const int lc = lane & 15, lq = lane >> 4;

  if (tid < 96) {
    int gt = t0 - 15 + tid;
    pa_s[tid] = (gt >= 0 && gt < TDIM) ? pa[b * TDIM + gt] : 0.0f;
  }
  for (int id = tid; id < FDIM * KW; id += 256)
    cw_s[id / KW][id % KW] = convw[id];
  if (tid < ADIM) {
    We_s[tid] = We[tid];
    dp_s[tid] = dec_p[b * ADIM + tid];
  }

  floatx4 acc[2][4];
  #pragma unroll
  for (int tt = 0; tt < 2; ++tt)
    #pragma unroll
    for (int aT = 0; aT < 4; ++aT)
      acc[tt][aT] = (floatx4){0.f, 0.f, 0.f, 0.f};

  const float* encB = enc + ((size_t)b * TDIM + t0) * EDIM;
  ushort2 cvp[4];

  for (int kt = 0; kt < 17; ++kt) {
    if (kt < 16) {
      const int k0 = kt * 32;
      #pragma unroll
      for (int r = 0; r < 2; ++r) {
        int id = tid + 256 * r;
        int row = id >> 3, c4 = id & 7;
        float4 v = *(const float4*)(encB + (size_t)row * EDIM + k0 + c4 * 4);
        stage4(&As[row][c4 * 4], v);
      }
      #pragma unroll
      for (int r = 0; r < 4; ++r) {
        int id = tid + 256 * r;
        int row = id >> 3, c4 = id & 7;
        float4 v = *(const float4*)(Wenc + (size_t)row * EDIM + k0 + c4 * 4);
        stage4(&Bs[row][c4 * 4], v);
      }
    } else {
      int tl = tid >> 2, fg = tid & 3;
      *(ushort2*)&As[tl][fg * 8 + 0] = cvp[0];
      *(ushort2*)&As[tl][fg * 8 + 2] = cvp[1];
      *(ushort2*)&As[tl][fg * 8 + 4] = cvp[2];
      *(ushort2*)&As[tl][fg * 8 + 6] = cvp[3];
      #pragma unroll
      for (int r = 0; r < 4; ++r) {
        int id = tid + 256 * r;
        int row = id >> 3, c4 = id & 7;
        float4 v = *(const float4*)(Wloc + (size_t)row * FDIM + c4 * 4);
        stage4(&Bs[row][c4 * 4], v);
      }
    }
    __syncthreads();
    if (kt == 0) {
      int tl = tid >> 2, fg = tid & 3;
      float cv[8];
      #pragma unroll
      for (int n = 0; n < 8; ++n) {
        int f = fg * 8 + n;
        float s = 0.f;
        #pragma unroll
        for (int k = 0; k < KW; ++k) s += pa_s[tl + k] * cw_s[f][k];
        cv[n] = s;
      }
      cvp[0] = pack_bf16(cv[0], cv[1]);
      cvp[1] = pack_bf16(cv[2], cv[3]);
      cvp[2] = pack_bf16(cv[4], cv[5]);
      cvp[3] = pack_bf16(cv[6], cv[7]);
    }
    short8 af[2], bf[4];
    #pragma unroll
    for (int tt = 0; tt < 2; ++tt)
      af[tt] = *(const short8*)&As[wt * 32 + tt * 16 + lc][lq * 8];
    #pragma unroll
    for (int aT = 0; aT < 4; ++aT)
      bf[aT] = *(const short8*)&Bs[wa * 64 + aT * 16 + lc][lq * 8];
    #pragma unroll
    for (int tt = 0; tt < 2; ++tt)
      #pragma unroll
      for (int aT = 0; aT < 4; ++aT)
        acc[tt][aT] = __builtin_amdgcn_mfma_f32_16x16x32_bf16(
            af[tt], bf[aT], acc[tt][aT], 0, 0, 0);
    __syncthreads();
  }

  float dpv[4], wev[4];
  #pragma unroll
  for (int aT = 0; aT < 4; ++aT) {
    int a = wa * 64 + aT * 16 + lc;
    dpv[aT] = dp_s[a];
    wev[aT] = We_s[a];
  }
  #pragma unroll
  for (int tt = 0; tt < 2; ++tt) {
    float es[4] = {0.f, 0.f, 0.f, 0.f};
    #pragma unroll
    for (int aT = 0; aT < 4; ++aT)
      #pragma unroll
      for (int i = 0; i < 4; ++i)
        es[i] += fast_tanh(acc[tt][aT][i] + dpv[aT]) * wev[aT];
    #pragma unroll
    for (int m = 1; m < 16; m <<= 1)
      #pragma unroll
      for (int i = 0; i < 4; ++i) es[i] += __shfl_xor(es[i], m, 64);
    if (lc == 0)
      #pragma unroll
      for (int i = 0; i < 4; ++i)
        epart[wa][wt * 32 + tt * 16 + lq * 4 + i] = es[i];
  }
  __syncthreads();
  if (tid < BM)
    energies[(size_t)b * TDIM + t0 + tid] = epart[0][tid] + epart[1][tid] + be[0];
}

// in-place softmax over T for each b
__global__ __launch_bounds__(256)
void softmax_kernel(float* __restrict__ attn) {
  int b = blockIdx.x;
  int tid = threadIdx.x;
  float* row = attn + (size_t)b * TDIM;
  float x0 = row[tid], x1 = row[tid + 256];
  float m = fmaxf(x0, x1);
  #pragma unroll
  for (int off = 32; off; off >>= 1) m = fmaxf(m, __shfl_xor(m, off, 64));
  __shared__ float redm[4];
  __shared__ float reds[4];
  int wid = tid >> 6, lane = tid & 63;
  if (lane == 0) redm[wid] = m;
  __syncthreads();
  m = fmaxf(fmaxf(redm[0], redm[1]), fmaxf(redm[2], redm[3]));
  float e0 = __expf(x0 - m), e1 = __expf(x1 - m);
  float s = e0 + e1;
  #pragma unroll
  for (int off = 32; off; off >>= 1) s += __shfl_xor(s, off, 64);
  if (lane == 0) reds[wid] = s;
  __syncthreads();
  s = reds[0] + reds[1] + reds[2] + reds[3];
  float inv = 1.0f / s;
  row[tid] = e0 * inv;
  row[tid + 256] = e1 * inv;
}

// ctx[b,e] += sum_t attn[b,t] * enc[b,t,e]
__global__ __launch_bounds__(256)
void context_kernel(const float* __restrict__ enc,
                    const float* __restrict__ attn,
                    float* __restrict__ ctx) {
  int e = blockIdx.x * 256 + threadIdx.x;
  int b = blockIdx.y;
  int tc = blockIdx.z * 128;
  const float* w = attn + (size_t)b * TDIM + tc;
  const float* ep = enc + ((size_t)b * TDIM + tc) * EDIM + e;
  float acc = 0.f;
  #pragma unroll 8
  for (int t = 0; t < 128; ++t) acc += w[t] * ep[(size_t)t * EDIM];
  atomicAdd(&ctx[(size_t)b * EDIM + e], acc);
}

}  // namespace

extern "C" void kernel_launch(void* const* d_in, const int* in_sizes, int n_in,
                              void* d_out, int out_size, void* d_ws, size_t ws_size,
                              hipStream_t stream) {
  const float* enc   = (const float*)d_in[0];
  const float* dec   = (const float*)d_in[1];
  const float* pa    = (const float*)d_in[2];
  const float* Wenc  = (const float*)d_in[3];
  const float* Wdec  = (const float*)d_in[4];
  const float* convw = (const float*)d_in[5];
  const float* Wloc  = (const float*)d_in[6];
  const float* We    = (const float*)d_in[7];
  const float* be    = (const float*)d_in[8];

  float* ctx  = (float*)d_out;
  float* attn = (float*)d_out + BATCH * EDIM;

  hipMemsetAsync(ctx, 0, (size_t)BATCH * EDIM * sizeof(float), stream);

  if (ws_size >= WS_NEEDED) {
    ushort* enc16  = (ushort*)d_ws;
    ushort* wenc16 = enc16 + N_ENC;
    ushort* wloc16 = enc16 + N_ENC + N_WENC;
    float*  dec_p  = (float*)(enc16 + N_BF);

    cvt_kernel<<<(unsigned)((N_BF + 2047) / 2048), 256, 0, stream>>>(
        enc, Wenc, Wloc, enc16);
    dim3 g1(BATCH, 4);
    dec_proj_kernel<<<g1, 256, 0, stream>>>(dec, Wdec, dec_p);
    dim3 g3(TDIM / BM, BATCH);
    energies_mfma_kernel<<<g3, 256, 0, stream>>>(enc16, wenc16, wloc16, pa,
                                                 convw, We, be, dec_p, attn);
  } else {
    float* dec_p = (float*)d_ws;
    dim3 g1(BATCH, 4);
    dec_proj_kernel<<<g1, 256, 0, stream>>>(dec, Wdec, dec_p);
    dim3 g3(TDIM / BM, BATCH);
    energies_fallback_kernel<<<g3, 256, 0, stream>>>(enc, Wenc, pa, convw,
                                                     Wloc, We, be, dec_p, attn);
  }

  softmax_kernel<<<BATCH, 256, 0, stream>>>(attn);

  dim3 g5(EDIM / 256, BATCH, TDIM / 128);
  context_kernel<<<g5, 256, 0, stream>>>(enc, attn, ctx);
}

// Round 4
// 282.886 us; speedup vs baseline: 2.1063x; 1.0089x over previous
//
#include <hip/hip_runtime.h>
#include <hip/hip_bf16.h>
#include <math.h>

namespace {
constexpr int EDIM  = 512;
constexpr int DDIM  = 1024;
constexpr int ADIM  = 128;
constexpr int FDIM  = 32;
constexpr int KW    = 31;
constexpr int BATCH = 128;
constexpr int TDIM  = 512;

constexpr int BM  = 64;   // t-tile
constexpr int LDA = 40;   // fallback path LDS stride

constexpr size_t N_ENC  = (size_t)BATCH * TDIM * EDIM;   // 33554432
constexpr size_t N_WENC = (size_t)ADIM * EDIM;           // 65536
constexpr size_t N_WLOC = (size_t)ADIM * FDIM;           // 4096
constexpr size_t N_BF   = N_ENC + N_WENC + N_WLOC;
constexpr size_t WS_NEEDED = N_BF * 2 + (size_t)BATCH * ADIM * 4;
constexpr int CVT_BLOCKS = (int)(N_BF / 2048);           // 16418 (exact)
constexpr int DEC_BLOCKS = BATCH * 4;                    // 512

typedef __attribute__((ext_vector_type(8))) short short8;
typedef __attribute__((ext_vector_type(4))) float floatx4;

__device__ __forceinline__ float fast_tanh(float x) {
  x = fminf(9.0f, fmaxf(-9.0f, x));
  float e = __expf(2.0f * x);
  return (e - 1.0f) / (e + 1.0f);
}

__device__ __forceinline__ ushort2 pack_bf16(float x, float y) {
  union { __hip_bfloat162 h; ushort2 u; } cv;
  cv.h = __float22bfloat162_rn(make_float2(x, y));
  return cv.u;
}

__device__ __forceinline__ float b2f(short u) {
  union { unsigned int i; float f; } c;
  c.i = ((unsigned int)(unsigned short)u) << 16;
  return c.f;
}

__device__ __forceinline__ void stage4(ushort* dst, const float4 v) {
  ushort2 lo = pack_bf16(v.x, v.y);
  ushort2 hi = pack_bf16(v.z, v.w);
  *(ushort4*)dst = make_ushort4(lo.x, lo.y, hi.x, hi.y);
}

// async 16-B global -> LDS DMA
__device__ __forceinline__ void async_ld16(const void* g, void* l) {
  __builtin_amdgcn_global_load_lds(
      (const __attribute__((address_space(1))) unsigned int*)g,
      (__attribute__((address_space(3))) unsigned int*)l, 16, 0, 0);
}

// ---- fused prep: fp32->bf16 cvt (enc|Wenc|Wloc) + dec projection ----------
__global__ __launch_bounds__(256)
void prep_kernel(const float* __restrict__ enc, const float* __restrict__ Wenc,
                 const float* __restrict__ Wloc, const float* __restrict__ dec,
                 const float* __restrict__ Wdec, ushort* __restrict__ out16,
                 float* __restrict__ dec_p) {
  int bid = blockIdx.x;
  if (bid < CVT_BLOCKS) {
    size_t e0 = (size_t)bid * 2048 + (size_t)threadIdx.x * 8;
    const float* s;
    size_t off;
    if (e0 < N_ENC) { s = enc; off = e0; }
    else if (e0 < N_ENC + N_WENC) { s = Wenc; off = e0 - N_ENC; }
    else { s = Wloc; off = e0 - (N_ENC + N_WENC); }
    float4 v0 = *(const float4*)(s + off);
    float4 v1 = *(const float4*)(s + off + 4);
    union { ushort2 u[4]; short8 v; } o;
    o.u[0] = pack_bf16(v0.x, v0.y); o.u[1] = pack_bf16(v0.z, v0.w);
    o.u[2] = pack_bf16(v1.x, v1.y); o.u[3] = pack_bf16(v1.z, v1.w);
    *(short8*)(out16 + e0) = o.v;
  } else {
    int id = bid - CVT_BLOCKS;
    int b = id >> 2, az = id & 3;
    int tid = threadIdx.x;
    int al = tid >> 3, seg = tid & 7;
    int a = az * 32 + al;
    const float* dv = dec + (size_t)b * DDIM;
    const float* wv = Wdec + (size_t)a * DDIM;
    float s = 0.f;
    #pragma unroll 8
    for (int it = 0; it < 32; ++it) {
      int d = it * 32 + seg * 4;
      float4 d4 = *(const float4*)(dv + d);
      float4 w4 = *(const float4*)(wv + d);
      s += d4.x * w4.x + d4.y * w4.y + d4.z * w4.z + d4.w * w4.w;
    }
    s += __shfl_xor(s, 1, 64);
    s += __shfl_xor(s, 2, 64);
    s += __shfl_xor(s, 4, 64);
    if (seg == 0) dec_p[b * ADIM + a] = s;
  }
}

// ---------------- energies v4: single-barrier double-buffered pipeline -----
// LDS map (ushorts): As0 [0,4096) | As1 [4096,8192) | Bs0 [8192,16384) |
// Bs1 [16384,24576) | epart (floats) [24576,24832).
// pa_s/cw_s overlay Bs1 (conv finishes before Bs1's first DMA).
__global__ __launch_bounds__(256, 3)
void energies_mfma_kernel(const ushort* __restrict__ enc16,
                          const ushort* __restrict__ wenc16,
                          const ushort* __restrict__ wloc16,
                          const float* __restrict__ pa,
                          const float* __restrict__ convw,
                          const float* __restrict__ We,
                          const float* __restrict__ be,
                          const float* __restrict__ dec_p,
                          float* __restrict__ energies) {
  __shared__ ushort lds[24832];
  float* pa_s  = (float*)(lds + 16384);   // 96 floats (Bs1 overlay)
  float* cw_s  = pa_s + 96;               // [32][33] floats (Bs1 overlay)
  float* epart = (float*)(lds + 24576);   // [2][64] floats

  const int tid  = threadIdx.x;
  const int b    = blockIdx.y;
  const int t0   = blockIdx.x * BM;
  const int wave = tid >> 6, lane = tid & 63;
  const int wt = wave >> 1, wa = wave & 1;
  const int lc = lane & 15, lq = lane >> 4;
  const int sw = lc & 7;

  if (tid < 96) {
    int gt = t0 - 15 + tid;
    pa_s[tid] = (gt >= 0 && gt < TDIM) ? pa[b * TDIM + gt] : 0.0f;
  }
  for (int id = tid; id < FDIM * KW; id += 256)
    cw_s[(id / KW) * 33 + (id % KW)] = convw[id];

  // staging descriptors
  const int iA0 = tid, iA1 = tid + 256;
  const ushort* gA0 = enc16 + (size_t)(b * TDIM + t0 + (iA0 >> 3)) * EDIM
                      + ((iA0 & 7) ^ ((iA0 >> 3) & 7)) * 8;
  const ushort* gA1 = enc16 + (size_t)(b * TDIM + t0 + (iA1 >> 3)) * EDIM
                      + ((iA1 & 7) ^ ((iA1 >> 3) & 7)) * 8;
  ushort* lA0 = lds + iA0 * 8;
  ushort* lA1 = lds + iA1 * 8;
  const ushort* gB[4];
  ushort* lB[4];
  #pragma unroll
  for (int r = 0; r < 4; ++r) {
    int idx = tid + r * 256;
    int row = idx >> 3, gc = (idx & 7) ^ (row & 7);
    gB[r] = wenc16 + (size_t)row * EDIM + gc * 8;
    lB[r] = lds + 8192 + idx * 8;
  }

  // prologue: issue tile 0 into buf0
  async_ld16(gA0, lA0); async_ld16(gA1, lA1);
  async_ld16(gB[0], lB[0]); async_ld16(gB[1], lB[1]);
  async_ld16(gB[2], lB[2]); async_ld16(gB[3], lB[3]);
  gA0 += 64; gA1 += 64;
  gB[0] += 64; gB[1] += 64; gB[2] += 64; gB[3] += 64;

  // wloc prefetch into registers (used at kt==7 loc staging)
  const int wi0 = tid, wi1 = tid + 256;
  short8 wl0 = *(const short8*)(wloc16 + (wi0 >> 2) * FDIM + (wi0 & 3) * 8);
  short8 wl1 = *(const short8*)(wloc16 + (wi1 >> 2) * FDIM + (wi1 & 3) * 8);

  __syncthreads();   // smalls + buf0 visible

  // location conv into registers (reads pa_s/cw_s in Bs1 overlay)
  const int tl = tid >> 2, fg = tid & 3;
  union { ushort2 u[4]; short8 v; } cvo;
  {
    float cv[8];
    #pragma unroll
    for (int n = 0; n < 8; ++n) {
      int f = fg * 8 + n;
      float s = 0.f;
      #pragma unroll
      for (int k = 0; k < KW; ++k) s += pa_s[tl + k] * cw_s[f * 33 + k];
      cv[n] = s;
    }
    cvo.u[0] = pack_bf16(cv[0], cv[1]);
    cvo.u[1] = pack_bf16(cv[2], cv[3]);
    cvo.u[2] = pack_bf16(cv[4], cv[5]);
    cvo.u[3] = pack_bf16(cv[6], cv[7]);
  }
  __syncthreads();   // conv reads done before Bs1's first DMA

  floatx4 acc[2][4];
  #pragma unroll
  for (int tt = 0; tt < 2; ++tt)
    #pragma unroll
    for (int aT = 0; aT < 4; ++aT)
      acc[tt][aT] = (floatx4){0.f, 0.f, 0.f, 0.f};

  for (int kt = 0; kt < 8; ++kt) {
    if (kt) __syncthreads();   // buf[kt&1] visible; other buffer's readers done
    const int cur = kt & 1;
    if (kt < 7) {
      const int aoff = (cur ^ 1) << 12;   // next A buffer (ushorts)
      const int boff = (cur ^ 1) << 13;   // next B buffer
      async_ld16(gA0, lA0 + aoff); async_ld16(gA1, lA1 + aoff);
      async_ld16(gB[0], lB[0] + boff); async_ld16(gB[1], lB[1] + boff);
      async_ld16(gB[2], lB[2] + boff); async_ld16(gB[3], lB[3] + boff);
      gA0 += 64; gA1 += 64;
      gB[0] += 64; gB[1] += 64; gB[2] += 64; gB[3] += 64;
    } else {
      // stage loc tiles into buf0 (cur==1): A=conv regs, B=wloc regs
      *(short8*)&lds[tl * 64 + (fg ^ (tl & 7)) * 8] = cvo.v;
      *(short8*)&lds[8192 + (wi0 >> 2) * 64 + ((wi0 & 3) ^ ((wi0 >> 2) & 7)) * 8] = wl0;
      *(short8*)&lds[8192 + (wi1 >> 2) * 64 + ((wi1 & 3) ^ ((wi1 >> 2) & 7)) * 8] = wl1;
    }
    const ushort* Ab = lds + (cur << 12);
    const ushort* Bb = lds + 8192 + (cur << 13);
    #pragma unroll
    for (int kk = 0; kk < 2; ++kk) {
      const int cco = ((kk * 4 + lq) ^ sw) * 8;
      short8 af[2], bf[4];
      #pragma unroll
      for (int tt = 0; tt < 2; ++tt)
        af[tt] = *(const short8*)&Ab[(wt * 32 + tt * 16 + lc) * 64 + cco];
      #pragma unroll
      for (int aT = 0; aT < 4; ++aT)
        bf[aT] = *(const short8*)&Bb[(wa * 64 + aT * 16 + lc) * 64 + cco];
      #pragma unroll
      for (int tt = 0; tt < 2; ++tt)
        #pragma unroll
        for (int aT = 0; aT < 4; ++aT)
          acc[tt][aT] = __builtin_amdgcn_mfma_f32_16x16x32_bf16(
              af[tt], bf[aT], acc[tt][aT], 0, 0, 0);
    }
  }
  __syncthreads();   // loc ds_writes visible

  // loc MFMA on buf0
  {
    const int cco = (lq ^ sw) * 8;
    short8 af[2], bf[4];
    #pragma unroll
    for (int tt = 0; tt < 2; ++tt)
      af[tt] = *(const short8*)&lds[(wt * 32 + tt * 16 + lc) * 64 + cco];
    #pragma unroll
    for (int aT = 0; aT < 4; ++aT)
      bf[aT] = *(const short8*)&lds[8192 + (wa * 64 + aT * 16 + lc) * 64 + cco];
    #pragma unroll
    for (int tt = 0; tt < 2; ++tt)
      #pragma unroll
      for (int aT = 0; aT < 4; ++aT)
        acc[tt][aT] = __builtin_amdgcn_mfma_f32_16x16x32_bf16(
            af[tt], bf[aT], acc[tt][aT], 0, 0, 0);
  }

  // epilogue: e[t] = sum_a tanh(acc + dec_p[a]) * We[a]
  float dpv[4], wev[4];
  #pragma unroll
  for (int aT = 0; aT < 4; ++aT) {
    int a = wa * 64 + aT * 16 + lc;
    dpv[aT] = dec_p[b * ADIM + a];
    wev[aT] = We[a];
  }
  #pragma unroll
  for (int tt = 0; tt < 2; ++tt) {
    float es[4] = {0.f, 0.f, 0.f, 0.f};
    #pragma unroll
    for (int aT = 0; aT < 4; ++aT)
      #pragma unroll
      for (int i = 0; i < 4; ++i)
        es[i] += fast_tanh(acc[tt][aT][i] + dpv[aT]) * wev[aT];
    #pragma unroll
    for (int m = 1; m < 16; m <<= 1)
      #pragma unroll
      for (int i = 0; i < 4; ++i) es[i] += __shfl_xor(es[i], m, 64);
    if (lc == 0)
      #pragma unroll
      for (int i = 0; i < 4; ++i)
        epart[wa * 64 + wt * 32 + tt * 16 + lq * 4 + i] = es[i];
  }
  __syncthreads();
  if (tid < BM)
    energies[(size_t)b * TDIM + t0 + tid] = epart[tid] + epart[64 + tid] + be[0];
}

// in-place softmax over T for each b
__global__ __launch_bounds__(256)
void softmax_kernel(float* __restrict__ attn) {
  int b = blockIdx.x;
  int tid = threadIdx.x;
  float* row = attn + (size_t)b * TDIM;
  float x0 = row[tid], x1 = row[tid + 256];
  float m = fmaxf(x0, x1);
  #pragma unroll
  for (int off = 32; off; off >>= 1) m = fmaxf(m, __shfl_xor(m, off, 64));
  __shared__ float redm[4];
  __shared__ float reds[4];
  int wid = tid >> 6, lane = tid & 63;
  if (lane == 0) redm[wid] = m;
  __syncthreads();
  m = fmaxf(fmaxf(redm[0], redm[1]), fmaxf(redm[2], redm[3]));
  float e0 = __expf(x0 - m), e1 = __expf(x1 - m);
  float s = e0 + e1;
  #pragma unroll
  for (int off = 32; off; off >>= 1) s += __shfl_xor(s, off, 64);
  if (lane == 0) reds[wid] = s;
  __syncthreads();
  s = reds[0] + reds[1] + reds[2] + reds[3];
  float inv = 1.0f / s;
  row[tid] = e0 * inv;
  row[tid + 256] = e1 * inv;
}

// ctx from bf16 enc: grid (4 tc, 128 b); wave covers 32 t's x full E
__global__ __launch_bounds__(256)
void context_bf16_kernel(const ushort* __restrict__ enc16,
                         const float* __restrict__ attn,
                         float* __restrict__ ctx) {
  __shared__ float red[4][512];
  const int b = blockIdx.y, tc = blockIdx.x * 128;
  const int wave = threadIdx.x >> 6, lane = threadIdx.x & 63;
  float acc[8] = {0.f, 0.f, 0.f, 0.f, 0.f, 0.f, 0.f, 0.f};
  const float* aw = attn + (size_t)b * TDIM + tc + wave * 32;
  const ushort* ep = enc16 + ((size_t)b * TDIM + tc + wave * 32) * EDIM + lane * 8;
  #pragma unroll 2
  for (int t = 0; t < 32; t += 2) {
    short8 v0 = *(const short8*)(ep + (size_t)t * EDIM);
    short8 v1 = *(const short8*)(ep + (size_t)(t + 1) * EDIM);
    float w0 = aw[t], w1 = aw[t + 1];
    #pragma unroll
    for (int j = 0; j < 8; ++j)
      acc[j] += w0 * b2f(v0[j]) + w1 * b2f(v1[j]);
  }
  #pragma unroll
  for (int j = 0; j < 8; ++j) red[wave][lane * 8 + j] = acc[j];
  __syncthreads();
  int e = threadIdx.x * 2;
  float s0 = red[0][e] + red[1][e] + red[2][e] + red[3][e];
  float s1 = red[0][e + 1] + red[1][e + 1] + red[2][e + 1] + red[3][e + 1];
  atomicAdd(&ctx[(size_t)b * EDIM + e], s0);
  atomicAdd(&ctx[(size_t)b * EDIM + e + 1], s1);
}

// ---------------- fallback path (no/too-small ws) --------------------------
__global__ __launch_bounds__(256)
void energies_fallback_kernel(const float* __restrict__ enc,
                              const float* __restrict__ Wenc,
                              const float* __restrict__ pa,
                              const float* __restrict__ convw,
                              const float* __restrict__ Wloc,
                              const float* __restrict__ We,
                              const float* __restrict__ be,
                              const float* __restrict__ dec_p,
                              float* __restrict__ energies) {
  __shared__ ushort As[BM][LDA];
  __shared__ ushort Bs[ADIM][LDA];
  __shared__ float pa_s[96];
  __shared__ float cw_s[FDIM][KW + 2];
  __shared__ float We_s[ADIM];
  __shared__ float dp_s[ADIM];
  __shared__ float epart[2][BM];

  const int tid  = threadIdx.x;
  const int b    = blockIdx.y;
  const int t0   = blockIdx.x * BM;
  const int wave = tid >> 6, lane = tid & 63;
  const int wt = wave >> 1, wa = wave & 1;
  const int lc = lane & 15, lq = lane >> 4;

  if (tid < 96) {
    int gt = t0 - 15 + tid;
    pa_s[tid] = (gt >= 0 && gt < TDIM) ? pa[b * TDIM + gt] : 0.0f;
  }
  for (int id = tid; id < FDIM * KW; id += 256)
    cw_s[id / KW][id % KW] = convw[id];
  if (tid < ADIM) {
    We_s[tid] = We[tid];
    dp_s[tid] = dec_p[b * ADIM + tid];
  }

  floatx4 acc[2][4];
  #pragma unroll
  for (int tt = 0; tt < 2; ++tt)
    #pragma unroll
    for (int aT = 0; aT < 4; ++aT)
      acc[tt][aT] = (floatx4){0.f, 0.f, 0.f, 0.f};

  const float* encB = enc + ((size_t)b * TDIM + t0) * EDIM;
  ushort2 cvp[4];

  for (int kt = 0; kt < 17; ++kt) {
    if (kt < 16) {
      const int k0 = kt * 32;
      #pragma unroll
      for (int r = 0; r < 2; ++r) {
        int id = tid + 256 * r;
        int row = id >> 3, c4 = id & 7;
        float4 v = *(const float4*)(encB + (size_t)row * EDIM + k0 + c4 * 4);
        stage4(&As[row][c4 * 4], v);
      }
      #pragma unroll
      for (int r = 0; r < 4; ++r) {
        int id = tid + 256 * r;
        int row = id >> 3, c4 = id & 7;
        float4 v = *(const float4*)(Wenc + (size_t)row * EDIM + k0 + c4 * 4);
        stage4(&Bs[row][c4 * 4], v);
      }
    } else {
      int tl = tid >> 2, fg = tid & 3;
      *(ushort2*)&As[tl][fg * 8 + 0] = cvp[0];
      *(ushort2*)&As[tl][fg * 8 + 2] = cvp[1];
      *(ushort2*)&As[tl][fg * 8 + 4] = cvp[2];
      *(ushort2*)&As[tl][fg * 8 + 6] = cvp[3];
      #pragma unroll
      for (int r = 0; r < 4; ++r) {
        int id = tid + 256 * r;
        int row = id >> 3, c4 = id & 7;
        float4 v = *(const float4*)(Wloc + (size_t)row * FDIM + c4 * 4);
        stage4(&Bs[row][c4 * 4], v);
      }
    }
    __syncthreads();
    if (kt == 0) {
      int tl = tid >> 2, fg = tid & 3;
      float cv[8];
      #pragma unroll
      for (int n = 0; n < 8; ++n) {
        int f = fg * 8 + n;
        float s = 0.f;
        #pragma unroll
        for (int k = 0; k < KW; ++k) s += pa_s[tl + k] * cw_s[f][k];
        cv[n] = s;
      }
      cvp[0] = pack_bf16(cv[0], cv[1]);
      cvp[1] = pack_bf16(cv[2], cv[3]);
      cvp[2] = pack_bf16(cv[4], cv[5]);
      cvp[3] = pack_bf16(cv[6], cv[7]);
    }
    short8 af[2], bf[4];
    #pragma unroll
    for (int tt = 0; tt < 2; ++tt)
      af[tt] = *(const short8*)&As[wt * 32 + tt * 16 + lc][lq * 8];
    #pragma unroll
    for (int aT = 0; aT < 4; ++aT)
      bf[aT] = *(const short8*)&Bs[wa * 64 + aT * 16 + lc][lq * 8];
    #pragma unroll
    for (int tt = 0; tt < 2; ++tt)
      #pragma unroll
      for (int aT = 0; aT < 4; ++aT)
        acc[tt][aT] = __builtin_amdgcn_mfma_f32_16x16x32_bf16(
            af[tt], bf[aT], acc[tt][aT], 0, 0, 0);
    __syncthreads();
  }

  float dpv[4], wev[4];
  #pragma unroll
  for (int aT = 0; aT < 4; ++aT) {
    int a = wa * 64 + aT * 16 + lc;
    dpv[aT] = dp_s[a];
    wev[aT] = We_s[a];
  }
  #pragma unroll
  for (int tt = 0; tt < 2; ++tt) {
    float es[4] = {0.f, 0.f, 0.f, 0.f};
    #pragma unroll
    for (int aT = 0; aT < 4; ++aT)
      #pragma unroll
      for (int i = 0; i < 4; ++i)
        es[i] += fast_tanh(acc[tt][aT][i] + dpv[aT]) * wev[aT];
    #pragma unroll
    for (int m = 1; m < 16; m <<= 1)
      #pragma unroll
      for (int i = 0; i < 4; ++i) es[i] += __shfl_xor(es[i], m, 64);
    if (lc == 0)
      #pragma unroll
      for (int i = 0; i < 4; ++i)
        epart[wa][wt * 32 + tt * 16 + lq * 4 + i] = es[i];
  }
  __syncthreads();
  if (tid < BM)
    energies[(size_t)b * TDIM + t0 + tid] = epart[0][tid] + epart[1][tid] + be[0];
}

__global__ __launch_bounds__(256)
void dec_proj_kernel(const float* __restrict__ dec,
                     const float* __restrict__ Wdec,
                     float* __restrict__ dec_p) {
  int b = blockIdx.x, az = blockIdx.y;
  int tid = threadIdx.x;
  int al = tid >> 3, seg = tid & 7;
  int a = az * 32 + al;
  const float* dv = dec + (size_t)b * DDIM;
  const float* wv = Wdec + (size_t)a * DDIM;
  float s = 0.f;
  #pragma unroll 8
  for (int it = 0; it < 32; ++it) {
    int d = it * 32 + seg * 4;
    float4 d4 = *(const float4*)(dv + d);
    float4 w4 = *(const float4*)(wv + d);
    s += d4.x * w4.x + d4.y * w4.y + d4.z * w4.z + d4.w * w4.w;
  }
  s += __shfl_xor(s, 1, 64);
  s += __shfl_xor(s, 2, 64);
  s += __shfl_xor(s, 4, 64);
  if (seg == 0) dec_p[b * ADIM + a] = s;
}

__global__ __launch_bounds__(256)
void context_f32_kernel(const float* __restrict__ enc,
                        const float* __restrict__ attn,
                        float* __restrict__ ctx) {
  int e = blockIdx.x * 256 + threadIdx.x;
  int b = blockIdx.y;
  int tc = blockIdx.z * 128;
  const float* w = attn + (size_t)b * TDIM + tc;
  const float* ep = enc + ((size_t)b * TDIM + tc) * EDIM + e;
  float acc = 0.f;
  #pragma unroll 8
  for (int t = 0; t < 128; ++t) acc += w[t] * ep[(size_t)t * EDIM];
  atomicAdd(&ctx[(size_t)b * EDIM + e], acc);
}

}  // namespace

extern "C" void kernel_launch(void* const* d_in, const int* in_sizes, int n_in,
                              void* d_out, int out_size, void* d_ws, size_t ws_size,
                              hipStream_t stream) {
  const float* enc   = (const float*)d_in[0];
  const float* dec   = (const float*)d_in[1];
  const float* pa    = (const float*)d_in[2];
  const float* Wenc  = (const float*)d_in[3];
  const float* Wdec  = (const float*)d_in[4];
  const float* convw = (const float*)d_in[5];
  const float* Wloc  = (const float*)d_in[6];
  const float* We    = (const float*)d_in[7];
  const float* be    = (const float*)d_in[8];

  float* ctx  = (float*)d_out;
  float* attn = (float*)d_out + BATCH * EDIM;

  hipMemsetAsync(ctx, 0, (size_t)BATCH * EDIM * sizeof(float), stream);

  if (ws_size >= WS_NEEDED) {
    ushort* enc16  = (ushort*)d_ws;
    ushort* wenc16 = enc16 + N_ENC;
    ushort* wloc16 = enc16 + N_ENC + N_WENC;
    float*  dec_p  = (float*)(enc16 + N_BF);

    prep_kernel<<<CVT_BLOCKS + DEC_BLOCKS, 256, 0, stream>>>(
        enc, Wenc, Wloc, dec, Wdec, enc16, dec_p);
    dim3 g3(TDIM / BM, BATCH);
    energies_mfma_kernel<<<g3, 256, 0, stream>>>(enc16, wenc16, wloc16, pa,
                                                 convw, We, be, dec_p, attn);
    softmax_kernel<<<BATCH, 256, 0, stream>>>(attn);
    dim3 g5(TDIM / 128, BATCH);
    context_bf16_kernel<<<g5, 256, 0, stream>>>(enc16, attn, ctx);
  } else {
    float* dec_p = (float*)d_ws;
    dim3 g1(BATCH, 4);
    dec_proj_kernel<<<g1, 256, 0, stream>>>(dec, Wdec, dec_p);
    dim3 g3(TDIM / BM, BATCH);
    energies_fallback_kernel<<<g3, 256, 0, stream>>>(enc, Wenc, pa, convw,
                                                     Wloc, We, be, dec_p, attn);
    softmax_kernel<<<BATCH, 256, 0, stream>>>(attn);
    dim3 g5(EDIM / 256, BATCH, TDIM / 128);
    context_f32_kernel<<<g5, 256, 0, stream>>>(enc, attn, ctx);
  }
}